// Round 1
// 344.523 us; speedup vs baseline: 1.1150x; 1.1150x over previous
//
#include <hip/hip_runtime.h>
#include <math.h>

#define T_TOT 65536   // N*L
#define C_DIM 256
#define M_DIM 128
#define NBLK  1024    // T_TOT/64 score blocks
#define SHRINKF 0.0025f
#define EPSF 1e-12f
#define QPAD 264      // LDS q-tile row stride (shorts): 528B rows -> conflict-free b128 reads

typedef __attribute__((ext_vector_type(8))) short bf8;
typedef __attribute__((ext_vector_type(4))) float f32x4;

__device__ inline unsigned pack2(float lo, float hi) {
    // two f32 -> two bf16 (truncation), lo in low half
    return __builtin_amdgcn_perm(__float_as_uint(hi), __float_as_uint(lo), 0x07060302u);
}
__device__ inline float b2f(short s) {
    return __uint_as_float(((unsigned)(unsigned short)s) << 16);
}

// ---------------- k_memcvt: mem -> bf16 ----------------
__global__ __launch_bounds__(256) void k_memcvt(const float* __restrict__ mem,
                                                short* __restrict__ mem_bf) {
    int idx = blockIdx.x * 256 + threadIdx.x;           // 4096 threads
    const float4* m4 = (const float4*)mem;
    uint2* mb = (uint2*)mem_bf;
    #pragma unroll
    for (int r = 0; r < 2; ++r) {
        int i = r * 4096 + idx;                          // 8192 float4 total
        float4 v = m4[i];
        mb[i] = make_uint2(pack2(v.x, v.y), pack2(v.z, v.w));
    }
}

// ---------------- k_prep_scores: fused q pass ----------------
// Per block: 64 t rows. Load q f32 (coalesced), write out[:, :256] + q_bf,
// stage bf16 tile in LDS, MFMA scores vs mem (D[t][m] layout -> in-lane t-reduce),
// online (mx,z) partials -> partials[m][blk] (transposed).
__global__ __launch_bounds__(256) void k_prep_scores(const float* __restrict__ q,
                                                     const short* __restrict__ mem_bf,
                                                     float* __restrict__ out,
                                                     short* __restrict__ q_bf,
                                                     float2* __restrict__ partials) {
    __shared__ short ldsQ[64 * QPAD];
    __shared__ float lds_mx[4][128];
    __shared__ float lds_z[4][128];
    int tid = threadIdx.x, bid = blockIdx.x;
    int lane = tid & 63, w = tid >> 6;
    int l15 = lane & 15, quad = lane >> 4;
    int t0 = bid * 64;

    const float4* q4 = (const float4*)q;
    float4* o4 = (float4*)out;
    uint2* qb = (uint2*)q_bf;
    #pragma unroll
    for (int j = 0; j < 16; ++j) {
        int i = j * 256 + tid;                            // 4096 float4 per block
        float4 v = q4[(size_t)bid * 4096 + i];
        int tl = i >> 6, c4 = i & 63;
        o4[(size_t)(t0 + tl) * 128 + c4] = v;             // out[:, :256] = q
        uint2 p = make_uint2(pack2(v.x, v.y), pack2(v.z, v.w));
        qb[(size_t)bid * 4096 + i] = p;                   // q_bf global
        *(uint2*)&ldsQ[tl * QPAD + c4 * 4] = p;           // LDS tile
    }
    __syncthreads();

    // MFMA: wave w handles t = t0 + w*16 + (quad*4+r), all 128 m.
    // sc = mfma(q_frag, mem_frag): row = t (quad*4+r), col = m (l15).
    f32x4 acc[8];
    #pragma unroll
    for (int mt = 0; mt < 8; ++mt) acc[mt] = (f32x4){0.f, 0.f, 0.f, 0.f};
    #pragma unroll
    for (int ks = 0; ks < 8; ++ks) {
        int k0 = ks * 32 + quad * 8;
        bf8 xq = *(const bf8*)&ldsQ[(w * 16 + l15) * QPAD + k0];
        #pragma unroll
        for (int mt = 0; mt < 8; ++mt) {
            bf8 ym = *(const bf8*)(mem_bf + (mt * 16 + l15) * C_DIM + k0);
            acc[mt] = __builtin_amdgcn_mfma_f32_16x16x32_bf16(xq, ym, acc[mt], 0, 0, 0);
        }
    }

    // per-m (mx, z) over this wave's 16 t: in-lane over r + cross-quad (xor 16/32)
    #pragma unroll
    for (int mt = 0; mt < 8; ++mt) {
        float mx = fmaxf(fmaxf(acc[mt][0], acc[mt][1]), fmaxf(acc[mt][2], acc[mt][3]));
        mx = fmaxf(mx, __shfl_xor(mx, 16, 64));
        mx = fmaxf(mx, __shfl_xor(mx, 32, 64));
        float z = __expf(acc[mt][0] - mx) + __expf(acc[mt][1] - mx)
                + __expf(acc[mt][2] - mx) + __expf(acc[mt][3] - mx);
        z += __shfl_xor(z, 16, 64);
        z += __shfl_xor(z, 32, 64);
        if (lane < 16) { lds_mx[w][mt * 16 + lane] = mx; lds_z[w][mt * 16 + lane] = z; }
    }
    __syncthreads();
    if (tid < 128) {
        int m = tid;
        float mx = lds_mx[0][m], z = lds_z[0][m];
        #pragma unroll
        for (int j = 1; j < 4; ++j) {
            float m2 = lds_mx[j][m], z2 = lds_z[j][m];
            float nm_ = fmaxf(mx, m2);
            z = z * __expf(mx - nm_) + z2 * __expf(m2 - nm_);
            mx = nm_;
        }
        partials[(size_t)m * NBLK + bid] = make_float2(mx, z);  // transposed [m][blk]
    }
}

// ---------------- k_update: per-m reduce + survivor + gate (one block per m) ----
__global__ __launch_bounds__(256) void k_update(const float2* __restrict__ partials,
                                                const short* __restrict__ q_bf,
                                                const short* __restrict__ mem_bf,
                                                const float* __restrict__ q,
                                                const float* __restrict__ mem,
                                                const float* __restrict__ U_w,
                                                const float* __restrict__ U_b,
                                                const float* __restrict__ W_w,
                                                const float* __restrict__ W_b,
                                                float* __restrict__ new_mem,
                                                short* __restrict__ nm_bf,
                                                short* __restrict__ nmT_bf) {
    __shared__ float smx[256], sz[256];
    __shared__ float ldsM[256], ldsA[256];
    __shared__ int flags[1024];
    __shared__ int fcnt;
    __shared__ float ps[256];
    __shared__ float hs[64];
    int m = blockIdx.x, tid = threadIdx.x;

    // online reduce over 1024 block-partials (coalesced row read, kept in regs)
    float2 pl[4];
    float mx = -3e38f, z = 0.f;
    #pragma unroll
    for (int jj = 0; jj < 4; ++jj) {
        pl[jj] = partials[(size_t)m * NBLK + jj * 256 + tid];
        float nm_ = fmaxf(mx, pl[jj].x);
        z = z * __expf(mx - nm_) + pl[jj].y * __expf(pl[jj].x - nm_);
        mx = nm_;
    }
    smx[tid] = mx; sz[tid] = z;
    __syncthreads();
    for (int s = 128; s > 0; s >>= 1) {
        if (tid < s) {
            float m2 = smx[tid + s], z2 = sz[tid + s];
            float nm_ = fmaxf(smx[tid], m2);
            sz[tid] = sz[tid] * __expf(smx[tid] - nm_) + z2 * __expf(m2 - nm_);
            smx[tid] = nm_;
        }
        __syncthreads();
    }
    float Mx = smx[0], Z = sz[0];
    float thr = Mx + logf(SHRINKF * Z);

    if (tid == 0) fcnt = 0;
    __syncthreads();
    #pragma unroll
    for (int jj = 0; jj < 4; ++jj)
        if (pl[jj].x > thr) { int pos = atomicAdd(&fcnt, 1); flags[pos] = jj * 256 + tid; }
    __syncthreads();
    int n = fcnt;

    float add_c = 0.f, l1_tot = 0.f;
    if (n > 0) {                                          // rare path (expected 0)
        float invZ = 1.f / Z;
        for (int f = 0; f < n; ++f) {
            int b = flags[f], tb = b * 64;
            int t = tid >> 2, seg = tid & 3;
            float p = 0.f;
            for (int k = seg * 64; k < seg * 64 + 64; ++k)
                p += b2f(mem_bf[m * C_DIM + k]) * b2f(q_bf[(size_t)(tb + t) * C_DIM + k]);
            ps[t * 4 + seg] = p;
            __syncthreads();
            if (tid < 64) {
                float s = ps[tid * 4] + ps[tid * 4 + 1] + ps[tid * 4 + 2] + ps[tid * 4 + 3];
                float a = __expf(s - Mx) * invZ;
                float d = a - SHRINKF;
                hs[tid] = d > 0.f ? d * a / (d + EPSF) : 0.f;
            }
            __syncthreads();
            for (int j = 0; j < 64; ++j) {
                float h = hs[j];
                if (h != 0.f) {
                    add_c += h * q[(size_t)(tb + j) * C_DIM + tid];
                    l1_tot += h;
                }
            }
            __syncthreads();
        }
    }

    // gate (c = tid)
    ldsM[tid] = mem[m * C_DIM + tid];
    ldsA[tid] = add_c / fmaxf(l1_tot, EPSF);
    __syncthreads();
    float acc = U_b[tid] + W_b[tid];
    const float4* uw = (const float4*)(U_w + (size_t)tid * C_DIM);
    const float4* ww = (const float4*)(W_w + (size_t)tid * C_DIM);
    const float4* lm = (const float4*)ldsM;
    const float4* la = (const float4*)ldsA;
    #pragma unroll 8
    for (int k = 0; k < 64; ++k) {
        float4 a = lm[k], u = uw[k];
        acc += a.x * u.x + a.y * u.y + a.z * u.z + a.w * u.w;
        float4 b = la[k], wv = ww[k];
        acc += b.x * wv.x + b.y * wv.y + b.z * wv.z + b.w * wv.w;
    }
    float g = 1.f / (1.f + __expf(-acc));
    float v = (1.f - g) * ldsM[tid] + g * ldsA[tid];
    new_mem[m * C_DIM + tid] = v;
    short bv = (short)(__float_as_uint(v) >> 16);
    nm_bf[m * C_DIM + tid] = bv;
    nmT_bf[tid * M_DIM + m] = bv;
}

// ---------------- k_read: fused read — swapped layouts, single-exp, vec stores --
__global__ __launch_bounds__(256) void k_read(const short* __restrict__ q_bf,
                                              const short* __restrict__ nm_bf,
                                              const short* __restrict__ nmT_bf,
                                              float* __restrict__ out,
                                              float* __restrict__ attn) {
    __shared__ short ldsW[64 * 136];    // W tile bf16 [t][m], +8 pad
    int tid = threadIdx.x;
    int lane = tid & 63, w = tid >> 6;
    int l15 = lane & 15, quad = lane >> 4;
    int t0 = blockIdx.x * 64;
    int tA = t0 + w * 16;
    int t = tA + l15;                   // this lane's t column

    // phase A: sc = nm @ q^T -> D[m][t]: row m = mt*16+quad*4+r, col t = l15
    f32x4 sc[8];
    #pragma unroll
    for (int mt = 0; mt < 8; ++mt) sc[mt] = (f32x4){0.f, 0.f, 0.f, 0.f};
    #pragma unroll
    for (int ks = 0; ks < 8; ++ks) {
        int k0 = ks * 32 + quad * 8;
        bf8 bq = *(const bf8*)(q_bf + (size_t)t * C_DIM + k0);
        #pragma unroll
        for (int mt = 0; mt < 8; ++mt) {
            bf8 an = *(const bf8*)(nm_bf + (mt * 16 + l15) * C_DIM + k0);
            sc[mt] = __builtin_amdgcn_mfma_f32_16x16x32_bf16(an, bq, sc[mt], 0, 0, 0);
        }
    }

    // phase B: per-t softmax over 128 m, fully in-lane (+2 shuffle pairs)
    float mx = -3e38f;
    #pragma unroll
    for (int mt = 0; mt < 8; ++mt) {
        #pragma unroll
        for (int r = 0; r < 4; ++r) mx = fmaxf(mx, sc[mt][r]);
    }
    mx = fmaxf(mx, __shfl_xor(mx, 16, 64));
    mx = fmaxf(mx, __shfl_xor(mx, 32, 64));
    float z = 0.f;
    #pragma unroll
    for (int mt = 0; mt < 8; ++mt) {
        #pragma unroll
        for (int r = 0; r < 4; ++r) {
            float e = __expf(sc[mt][r] - mx);
            sc[mt][r] = e;                       // cache exp (single-exp)
            z += e;
        }
    }
    z += __shfl_xor(z, 16, 64);
    z += __shfl_xor(z, 32, 64);
    float invZ = 1.f / z;
    float l1 = 0.f;
    #pragma unroll
    for (int mt = 0; mt < 8; ++mt) {
        #pragma unroll
        for (int r = 0; r < 4; ++r) {
            float a = sc[mt][r] * invZ;
            float d = a - SHRINKF;
            float h = d > 0.f ? d * a / (d + EPSF) : 0.f;
            sc[mt][r] = h;
            l1 += h;
        }
    }
    l1 += __shfl_xor(l1, 16, 64);
    l1 += __shfl_xor(l1, 32, 64);
    float invL1 = 1.f / fmaxf(l1, EPSF);

    float4* at4 = (float4*)(attn + (size_t)t * M_DIM + quad * 4);
    #pragma unroll
    for (int mt = 0; mt < 8; ++mt) {
        float w0 = sc[mt][0] * invL1, w1 = sc[mt][1] * invL1;
        float w2 = sc[mt][2] * invL1, w3 = sc[mt][3] * invL1;
        at4[mt * 4] = make_float4(w0, w1, w2, w3);                  // attn float4
        *(uint2*)&ldsW[(w * 16 + l15) * 136 + mt * 16 + quad * 4] =
            make_uint2(pack2(w0, w1), pack2(w2, w3));               // W bf16 packed
    }
    __syncthreads();

    // phase C: pv = nm^T @ W^T -> D[c][t]: row c = ct*16+quad*4+r, col t = l15
    f32x4 pv[16];
    #pragma unroll
    for (int ct = 0; ct < 16; ++ct) pv[ct] = (f32x4){0.f, 0.f, 0.f, 0.f};
    #pragma unroll
    for (int ks = 0; ks < 4; ++ks) {
        int k0 = ks * 32 + quad * 8;
        bf8 bw = *(const bf8*)&ldsW[(w * 16 + l15) * 136 + k0];
        #pragma unroll
        for (int ct = 0; ct < 16; ++ct) {
            bf8 an = *(const bf8*)(nmT_bf + (ct * 16 + l15) * M_DIM + k0);
            pv[ct] = __builtin_amdgcn_mfma_f32_16x16x32_bf16(an, bw, pv[ct], 0, 0, 0);
        }
    }
    float4* o4 = (float4*)(out + (size_t)t * 512 + 256 + quad * 4);
    #pragma unroll
    for (int ct = 0; ct < 16; ++ct)
        o4[ct * 4] = make_float4(pv[ct][0], pv[ct][1], pv[ct][2], pv[ct][3]);  // out float4
}

extern "C" void kernel_launch(void* const* d_in, const int* in_sizes, int n_in,
                              void* d_out, int out_size, void* d_ws, size_t ws_size,
                              hipStream_t stream) {
    const float* q   = (const float*)d_in[0];
    const float* mem = (const float*)d_in[1];
    const float* U_w = (const float*)d_in[2];
    const float* U_b = (const float*)d_in[3];
    const float* W_w = (const float*)d_in[4];
    const float* W_b = (const float*)d_in[5];

    float* out     = (float*)d_out;                     // (T, 512)
    float* attn    = out + (size_t)T_TOT * 2 * C_DIM;   // (T, 128)
    float* new_mem = attn + (size_t)T_TOT * M_DIM;      // (M, 256)

    char* ws = (char*)d_ws;
    short*  q_bf     = (short*)ws;    ws += (size_t)T_TOT * C_DIM * 2;   // 33.55 MB
    short*  mem_bf   = (short*)ws;    ws += M_DIM * C_DIM * 2;
    short*  nm_bf    = (short*)ws;    ws += M_DIM * C_DIM * 2;
    short*  nmT_bf   = (short*)ws;    ws += M_DIM * C_DIM * 2;
    float2* partials = (float2*)ws;   ws += (size_t)NBLK * M_DIM * 8;    // 1 MB [m][blk]

    k_memcvt<<<16, 256, 0, stream>>>(mem, mem_bf);
    k_prep_scores<<<NBLK, 256, 0, stream>>>(q, mem_bf, out, q_bf, partials);
    k_update<<<M_DIM, 256, 0, stream>>>(partials, q_bf, mem_bf, q, mem,
                                        U_w, U_b, W_w, W_b, new_mem, nm_bf, nmT_bf);
    k_read<<<NBLK, 256, 0, stream>>>(q_bf, nm_bf, nmT_bf, out, attn);
}

// Round 5
// 333.034 us; speedup vs baseline: 1.1535x; 1.0345x over previous
//
#include <hip/hip_runtime.h>
#include <math.h>

#define T_TOT 65536   // N*L
#define C_DIM 256
#define M_DIM 128
#define NBLK  1024    // T_TOT/64 score blocks
#define SHRINKF 0.0025f
#define EPSF 1e-12f
#define QPAD 264      // LDS q-tile row stride (shorts): 528B rows -> conflict-free b128 reads

typedef __attribute__((ext_vector_type(8))) short bf8;
typedef __attribute__((ext_vector_type(4))) float f32x4;
// raw clang vector types for nontemporal builtins (HIP_vector_type is rejected)
typedef __attribute__((ext_vector_type(4))) float f4raw;
typedef __attribute__((ext_vector_type(2))) unsigned u2raw;

__device__ inline unsigned pack2(float lo, float hi) {
    // two f32 -> two bf16 (truncation), lo in low half
    return __builtin_amdgcn_perm(__float_as_uint(hi), __float_as_uint(lo), 0x07060302u);
}
__device__ inline float b2f(short s) {
    return __uint_as_float(((unsigned)(unsigned short)s) << 16);
}

// ---------------- k_memcvt: mem -> bf16 ----------------
__global__ __launch_bounds__(256) void k_memcvt(const float* __restrict__ mem,
                                                short* __restrict__ mem_bf) {
    int idx = blockIdx.x * 256 + threadIdx.x;           // 4096 threads
    const f4raw* m4 = (const f4raw*)mem;
    u2raw* mb = (u2raw*)mem_bf;
    #pragma unroll
    for (int r = 0; r < 2; ++r) {
        int i = r * 4096 + idx;                          // 8192 float4 total
        f4raw v = m4[i];
        u2raw p; p[0] = pack2(v[0], v[1]); p[1] = pack2(v[2], v[3]);
        mb[i] = p;
    }
}

// ---------------- k_prep_scores: fused q pass ----------------
// Per block: 64 t rows. Load q f32 (NT, streamed once), write out[:, :256] (NT)
// + q_bf (NT), stage bf16 tile in LDS, MFMA scores vs mem (D[t][m] layout ->
// in-lane t-reduce), online (mx,z) partials -> partials[m][blk] (transposed).
__global__ __launch_bounds__(256) void k_prep_scores(const float* __restrict__ q,
                                                     const short* __restrict__ mem_bf,
                                                     float* __restrict__ out,
                                                     short* __restrict__ q_bf,
                                                     float2* __restrict__ partials) {
    __shared__ short ldsQ[64 * QPAD];
    __shared__ float lds_mx[4][128];
    __shared__ float lds_z[4][128];
    int tid = threadIdx.x, bid = blockIdx.x;
    int lane = tid & 63, w = tid >> 6;
    int l15 = lane & 15, quad = lane >> 4;
    int t0 = bid * 64;

    const f4raw* q4 = (const f4raw*)q;
    f4raw* o4 = (f4raw*)out;
    u2raw* qb = (u2raw*)q_bf;
    #pragma unroll
    for (int j = 0; j < 16; ++j) {
        int i = j * 256 + tid;                            // 4096 float4 per block
        f4raw v = __builtin_nontemporal_load(&q4[(size_t)bid * 4096 + i]);
        int tl = i >> 6, c4 = i & 63;
        __builtin_nontemporal_store(v, &o4[(size_t)(t0 + tl) * 128 + c4]);  // out[:, :256] = q
        u2raw p; p[0] = pack2(v[0], v[1]); p[1] = pack2(v[2], v[3]);
        __builtin_nontemporal_store(p, &qb[(size_t)bid * 4096 + i]);        // q_bf global
        *(u2raw*)&ldsQ[tl * QPAD + c4 * 4] = p;           // LDS tile
    }
    __syncthreads();

    // MFMA: wave w handles t = t0 + w*16 + (quad*4+r), all 128 m.
    // sc = mfma(q_frag, mem_frag): row = t (quad*4+r), col = m (l15).
    f32x4 acc[8];
    #pragma unroll
    for (int mt = 0; mt < 8; ++mt) acc[mt] = (f32x4){0.f, 0.f, 0.f, 0.f};
    #pragma unroll
    for (int ks = 0; ks < 8; ++ks) {
        int k0 = ks * 32 + quad * 8;
        bf8 xq = *(const bf8*)&ldsQ[(w * 16 + l15) * QPAD + k0];
        #pragma unroll
        for (int mt = 0; mt < 8; ++mt) {
            bf8 ym = *(const bf8*)(mem_bf + (mt * 16 + l15) * C_DIM + k0);
            acc[mt] = __builtin_amdgcn_mfma_f32_16x16x32_bf16(xq, ym, acc[mt], 0, 0, 0);
        }
    }

    // per-m (mx, z) over this wave's 16 t: in-lane over r + cross-quad (xor 16/32)
    #pragma unroll
    for (int mt = 0; mt < 8; ++mt) {
        float mx = fmaxf(fmaxf(acc[mt][0], acc[mt][1]), fmaxf(acc[mt][2], acc[mt][3]));
        mx = fmaxf(mx, __shfl_xor(mx, 16, 64));
        mx = fmaxf(mx, __shfl_xor(mx, 32, 64));
        float z = __expf(acc[mt][0] - mx) + __expf(acc[mt][1] - mx)
                + __expf(acc[mt][2] - mx) + __expf(acc[mt][3] - mx);
        z += __shfl_xor(z, 16, 64);
        z += __shfl_xor(z, 32, 64);
        if (lane < 16) { lds_mx[w][mt * 16 + lane] = mx; lds_z[w][mt * 16 + lane] = z; }
    }
    __syncthreads();
    if (tid < 128) {
        int m = tid;
        float mx = lds_mx[0][m], z = lds_z[0][m];
        #pragma unroll
        for (int j = 1; j < 4; ++j) {
            float m2 = lds_mx[j][m], z2 = lds_z[j][m];
            float nm_ = fmaxf(mx, m2);
            z = z * __expf(mx - nm_) + z2 * __expf(m2 - nm_);
            mx = nm_;
        }
        partials[(size_t)m * NBLK + bid] = make_float2(mx, z);  // transposed [m][blk]
    }
}

// ---------------- k_update: per-m reduce + survivor + gate (one block per m) ----
__global__ __launch_bounds__(256) void k_update(const float2* __restrict__ partials,
                                                const short* __restrict__ q_bf,
                                                const short* __restrict__ mem_bf,
                                                const float* __restrict__ q,
                                                const float* __restrict__ mem,
                                                const float* __restrict__ U_w,
                                                const float* __restrict__ U_b,
                                                const float* __restrict__ W_w,
                                                const float* __restrict__ W_b,
                                                float* __restrict__ new_mem,
                                                short* __restrict__ nm_bf,
                                                short* __restrict__ nmT_bf) {
    __shared__ float smx[256], sz[256];
    __shared__ float ldsM[256], ldsA[256];
    __shared__ int flags[1024];
    __shared__ int fcnt;
    __shared__ float ps[256];
    __shared__ float hs[64];
    int m = blockIdx.x, tid = threadIdx.x;

    // online reduce over 1024 block-partials (coalesced row read, kept in regs)
    float2 pl[4];
    float mx = -3e38f, z = 0.f;
    #pragma unroll
    for (int jj = 0; jj < 4; ++jj) {
        pl[jj] = partials[(size_t)m * NBLK + jj * 256 + tid];
        float nm_ = fmaxf(mx, pl[jj].x);
        z = z * __expf(mx - nm_) + pl[jj].y * __expf(pl[jj].x - nm_);
        mx = nm_;
    }
    smx[tid] = mx; sz[tid] = z;
    __syncthreads();
    for (int s = 128; s > 0; s >>= 1) {
        if (tid < s) {
            float m2 = smx[tid + s], z2 = sz[tid + s];
            float nm_ = fmaxf(smx[tid], m2);
            sz[tid] = sz[tid] * __expf(smx[tid] - nm_) + z2 * __expf(m2 - nm_);
            smx[tid] = nm_;
        }
        __syncthreads();
    }
    float Mx = smx[0], Z = sz[0];
    float thr = Mx + logf(SHRINKF * Z);

    if (tid == 0) fcnt = 0;
    __syncthreads();
    #pragma unroll
    for (int jj = 0; jj < 4; ++jj)
        if (pl[jj].x > thr) { int pos = atomicAdd(&fcnt, 1); flags[pos] = jj * 256 + tid; }
    __syncthreads();
    int n = fcnt;

    float add_c = 0.f, l1_tot = 0.f;
    if (n > 0) {                                          // rare path (expected 0)
        float invZ = 1.f / Z;
        for (int f = 0; f < n; ++f) {
            int b = flags[f], tb = b * 64;
            int t = tid >> 2, seg = tid & 3;
            float p = 0.f;
            for (int k = seg * 64; k < seg * 64 + 64; ++k)
                p += b2f(mem_bf[m * C_DIM + k]) * b2f(q_bf[(size_t)(tb + t) * C_DIM + k]);
            ps[t * 4 + seg] = p;
            __syncthreads();
            if (tid < 64) {
                float s = ps[tid * 4] + ps[tid * 4 + 1] + ps[tid * 4 + 2] + ps[tid * 4 + 3];
                float a = __expf(s - Mx) * invZ;
                float d = a - SHRINKF;
                hs[tid] = d > 0.f ? d * a / (d + EPSF) : 0.f;
            }
            __syncthreads();
            for (int j = 0; j < 64; ++j) {
                float h = hs[j];
                if (h != 0.f) {
                    add_c += h * q[(size_t)(tb + j) * C_DIM + tid];
                    l1_tot += h;
                }
            }
            __syncthreads();
        }
    }

    // gate (c = tid)
    ldsM[tid] = mem[m * C_DIM + tid];
    ldsA[tid] = add_c / fmaxf(l1_tot, EPSF);
    __syncthreads();
    float acc = U_b[tid] + W_b[tid];
    const float4* uw = (const float4*)(U_w + (size_t)tid * C_DIM);
    const float4* ww = (const float4*)(W_w + (size_t)tid * C_DIM);
    const float4* lm = (const float4*)ldsM;
    const float4* la = (const float4*)ldsA;
    #pragma unroll 8
    for (int k = 0; k < 64; ++k) {
        float4 a = lm[k], u = uw[k];
        acc += a.x * u.x + a.y * u.y + a.z * u.z + a.w * u.w;
        float4 b = la[k], wv = ww[k];
        acc += b.x * wv.x + b.y * wv.y + b.z * wv.z + b.w * wv.w;
    }
    float g = 1.f / (1.f + __expf(-acc));
    float v = (1.f - g) * ldsM[tid] + g * ldsA[tid];
    new_mem[m * C_DIM + tid] = v;
    short bv = (short)(__float_as_uint(v) >> 16);
    nm_bf[m * C_DIM + tid] = bv;
    nmT_bf[tid * M_DIM + m] = bv;
}

// ---------------- k_read: fused read — swapped layouts, single-exp, NT stores --
__global__ __launch_bounds__(256) void k_read(const short* __restrict__ q_bf,
                                              const short* __restrict__ nm_bf,
                                              const short* __restrict__ nmT_bf,
                                              float* __restrict__ out,
                                              float* __restrict__ attn) {
    __shared__ short ldsW[64 * 136];    // W tile bf16 [t][m], +8 pad
    int tid = threadIdx.x;
    int lane = tid & 63, w = tid >> 6;
    int l15 = lane & 15, quad = lane >> 4;
    int t0 = blockIdx.x * 64;
    int tA = t0 + w * 16;
    int t = tA + l15;                   // this lane's t column

    // phase A: sc = nm @ q^T -> D[m][t]: row m = mt*16+quad*4+r, col t = l15
    f32x4 sc[8];
    #pragma unroll
    for (int mt = 0; mt < 8; ++mt) sc[mt] = (f32x4){0.f, 0.f, 0.f, 0.f};
    #pragma unroll
    for (int ks = 0; ks < 8; ++ks) {
        int k0 = ks * 32 + quad * 8;
        bf8 bq = __builtin_nontemporal_load((const bf8*)(q_bf + (size_t)t * C_DIM + k0));
        #pragma unroll
        for (int mt = 0; mt < 8; ++mt) {
            bf8 an = *(const bf8*)(nm_bf + (mt * 16 + l15) * C_DIM + k0);
            sc[mt] = __builtin_amdgcn_mfma_f32_16x16x32_bf16(an, bq, sc[mt], 0, 0, 0);
        }
    }

    // phase B: per-t softmax over 128 m, fully in-lane (+2 shuffle pairs)
    float mx = -3e38f;
    #pragma unroll
    for (int mt = 0; mt < 8; ++mt) {
        #pragma unroll
        for (int r = 0; r < 4; ++r) mx = fmaxf(mx, sc[mt][r]);
    }
    mx = fmaxf(mx, __shfl_xor(mx, 16, 64));
    mx = fmaxf(mx, __shfl_xor(mx, 32, 64));
    float z = 0.f;
    #pragma unroll
    for (int mt = 0; mt < 8; ++mt) {
        #pragma unroll
        for (int r = 0; r < 4; ++r) {
            float e = __expf(sc[mt][r] - mx);
            sc[mt][r] = e;                       // cache exp (single-exp)
            z += e;
        }
    }
    z += __shfl_xor(z, 16, 64);
    z += __shfl_xor(z, 32, 64);
    float invZ = 1.f / z;
    float l1 = 0.f;
    #pragma unroll
    for (int mt = 0; mt < 8; ++mt) {
        #pragma unroll
        for (int r = 0; r < 4; ++r) {
            float a = sc[mt][r] * invZ;
            float d = a - SHRINKF;
            float h = d > 0.f ? d * a / (d + EPSF) : 0.f;
            sc[mt][r] = h;
            l1 += h;
        }
    }
    l1 += __shfl_xor(l1, 16, 64);
    l1 += __shfl_xor(l1, 32, 64);
    float invL1 = 1.f / fmaxf(l1, EPSF);

    f4raw* at4 = (f4raw*)(attn + (size_t)t * M_DIM + quad * 4);
    #pragma unroll
    for (int mt = 0; mt < 8; ++mt) {
        float w0 = sc[mt][0] * invL1, w1 = sc[mt][1] * invL1;
        float w2 = sc[mt][2] * invL1, w3 = sc[mt][3] * invL1;
        f4raw av; av[0] = w0; av[1] = w1; av[2] = w2; av[3] = w3;
        __builtin_nontemporal_store(av, &at4[mt * 4]);              // attn float4
        u2raw p; p[0] = pack2(w0, w1); p[1] = pack2(w2, w3);
        *(u2raw*)&ldsW[(w * 16 + l15) * 136 + mt * 16 + quad * 4] = p;  // W bf16 packed
    }
    __syncthreads();

    // phase C: pv = nm^T @ W^T -> D[c][t]: row c = ct*16+quad*4+r, col t = l15
    f32x4 pv[16];
    #pragma unroll
    for (int ct = 0; ct < 16; ++ct) pv[ct] = (f32x4){0.f, 0.f, 0.f, 0.f};
    #pragma unroll
    for (int ks = 0; ks < 4; ++ks) {
        int k0 = ks * 32 + quad * 8;
        bf8 bw = *(const bf8*)&ldsW[(w * 16 + l15) * 136 + k0];
        #pragma unroll
        for (int ct = 0; ct < 16; ++ct) {
            bf8 an = *(const bf8*)(nmT_bf + (ct * 16 + l15) * M_DIM + k0);
            pv[ct] = __builtin_amdgcn_mfma_f32_16x16x32_bf16(an, bw, pv[ct], 0, 0, 0);
        }
    }
    f4raw* o4 = (f4raw*)(out + (size_t)t * 512 + 256 + quad * 4);
    #pragma unroll
    for (int ct = 0; ct < 16; ++ct) {
        f4raw ov; ov[0] = pv[ct][0]; ov[1] = pv[ct][1]; ov[2] = pv[ct][2]; ov[3] = pv[ct][3];
        __builtin_nontemporal_store(ov, &o4[ct * 4]);               // out float4
    }
}

extern "C" void kernel_launch(void* const* d_in, const int* in_sizes, int n_in,
                              void* d_out, int out_size, void* d_ws, size_t ws_size,
                              hipStream_t stream) {
    const float* q   = (const float*)d_in[0];
    const float* mem = (const float*)d_in[1];
    const float* U_w = (const float*)d_in[2];
    const float* U_b = (const float*)d_in[3];
    const float* W_w = (const float*)d_in[4];
    const float* W_b = (const float*)d_in[5];

    float* out     = (float*)d_out;                     // (T, 512)
    float* attn    = out + (size_t)T_TOT * 2 * C_DIM;   // (T, 128)
    float* new_mem = attn + (size_t)T_TOT * M_DIM;      // (M, 256)

    char* ws = (char*)d_ws;
    short*  q_bf     = (short*)ws;    ws += (size_t)T_TOT * C_DIM * 2;   // 33.55 MB
    short*  mem_bf   = (short*)ws;    ws += M_DIM * C_DIM * 2;
    short*  nm_bf    = (short*)ws;    ws += M_DIM * C_DIM * 2;
    short*  nmT_bf   = (short*)ws;    ws += M_DIM * C_DIM * 2;
    float2* partials = (float2*)ws;   ws += (size_t)NBLK * M_DIM * 8;    // 1 MB [m][blk]

    k_memcvt<<<16, 256, 0, stream>>>(mem, mem_bf);
    k_prep_scores<<<NBLK, 256, 0, stream>>>(q, mem_bf, out, q_bf, partials);
    k_update<<<M_DIM, 256, 0, stream>>>(partials, q_bf, mem_bf, q, mem,
                                        U_w, U_b, W_w, W_b, new_mem, nm_bf, nmT_bf);
    k_read<<<NBLK, 256, 0, stream>>>(q_bf, nm_bf, nmT_bf, out, attn);
}